// Round 3
// baseline (634.224 us; speedup 1.0000x reference)
//
#include <hip/hip_runtime.h>

#define EE      640000
#define NNODES_ 10000
#define NG      64
#define DN      128
#define DE      32
#define HID     128
#define DOUT    64
#define NMT     (EE / 16)
#define NBLK    768

// ---- workspace float-element offsets (fixed part = 414,752 bytes) ----
#define ACCF  0        // [64][128] per-graph sum of a
#define CNTF  8192     // [64] edge count per graph
#define S1F   8256     // [128] global sum(a)
#define S2F   8384     // [128] global sum(a^2)
#define GXF   8512     // [64][128] per-graph node sums
#define O1F   16704    // [64][128] mlp2 hidden
#define FLGF  24896    // int flags: [0]=floats-are-bf16, [1]=ints-are-i64
#define W1F_  24904    // 160*128
#define B1F_  45384
#define G1F_  45512
#define BE1F_ 45640
#define W2F_  45768    // 128*128
#define B2F_  62152
#define W3F_  62280    // 256*128
#define B3F_  95048
#define G3F_  95176
#define BE3F_ 95304
#define W4F_  95432    // 128*64
#define B4F_  103624   // 64
#define WSFIX 103688   // end of fixed part (floats)
#define XBFF  103688   // optional bf16 x copy (1,280,000 bf16 = 2.56 MB), byte off 414752 (16B aligned)

typedef __bf16 bf16x8 __attribute__((ext_vector_type(8)));
typedef float  f32x4  __attribute__((ext_vector_type(4)));

__device__ __forceinline__ float lrelu(float v) { return v > 0.f ? v : 0.01f * v; }

// ---- K0: dtype sniffer (deterministic on input data) ----
__global__ void k_sniff(const unsigned* __restrict__ xw, const unsigned* __restrict__ ew,
                        float* __restrict__ ws) {
  const int l = threadIdx.x;  // 64
  const unsigned w = xw[l];
  const unsigned ex = (w >> 7) & 0xFFu;          // bf16 exponent if packed bf16 pair
  int cb = (ex >= 100u && ex <= 140u) ? 1 : 0;   // bf16: ~64/64; fp32: ~10/64
  int ci = (ew[2 * l + 1] == 0u) ? 1 : 0;        // int64: odd words zero
#pragma unroll
  for (int s = 1; s < 64; s <<= 1) { cb += __shfl_xor(cb, s); ci += __shfl_xor(ci, s); }
  if (l == 0) { int* f = (int*)(ws + FLGF); f[0] = (cb >= 48); f[1] = (ci >= 60); }
}

__device__ __forceinline__ void cpyw(float* dst, const void* src, int n, int isb,
                                     int gtid, int gs) {
  if (isb) { const __bf16* s = (const __bf16*)src;
    for (int i = gtid; i < n; i += gs) dst[i] = (float)s[i];
  } else { const float* s = (const float*)src;
    for (int i = gtid; i < n; i += gs) dst[i] = s[i]; }
}

// ---- K1: zero accumulators, weights -> fp32 in ws, optional x -> bf16 ----
__global__ __launch_bounds__(256) void k_norm(
    const void* __restrict__ x,
    const void* W1, const void* b1, const void* g1, const void* be1,
    const void* W2, const void* b2, const void* W3, const void* b3,
    const void* g3, const void* be3, const void* W4, const void* b4,
    float* __restrict__ ws, const int use_xbf) {
  const int gtid = blockIdx.x * 256 + threadIdx.x;
  const int gs = gridDim.x * 256;
  const int isb = ((const int*)(ws + FLGF))[0];
  for (int i = gtid; i < 8512; i += gs) ws[i] = 0.f;
  cpyw(ws + W1F_, W1, 160 * HID, isb, gtid, gs);
  cpyw(ws + B1F_, b1, HID, isb, gtid, gs);
  cpyw(ws + G1F_, g1, HID, isb, gtid, gs);
  cpyw(ws + BE1F_, be1, HID, isb, gtid, gs);
  cpyw(ws + W2F_, W2, HID * HID, isb, gtid, gs);
  cpyw(ws + B2F_, b2, HID, isb, gtid, gs);
  cpyw(ws + W3F_, W3, 256 * HID, isb, gtid, gs);
  cpyw(ws + B3F_, b3, HID, isb, gtid, gs);
  cpyw(ws + G3F_, g3, HID, isb, gtid, gs);
  cpyw(ws + BE3F_, be3, HID, isb, gtid, gs);
  cpyw(ws + W4F_, W4, HID * DOUT, isb, gtid, gs);
  cpyw(ws + B4F_, b4, DOUT, isb, gtid, gs);
  if (use_xbf && !isb) {
    __bf16* xbf = (__bf16*)(ws + XBFF);
    const float* xs = (const float*)x;
    for (int i = gtid; i < NNODES_ * DN; i += gs) xbf[i] = (__bf16)xs[i];
  }
}

// ---- K2: per-graph node-feature sums (batch sorted), direct from inputs ----
__global__ __launch_bounds__(256) void k_gx(
    const void* __restrict__ x, const void* __restrict__ batch, float* __restrict__ ws) {
  const int b = blockIdx.x, tid = threadIdx.x;
  const int isb = ((const int*)(ws + FLGF))[0];
  const int isi = ((const int*)(ws + FLGF))[1];
  const int* bt = (const int*)batch;
#define BATV(i) ((isi ? bt[2 * (i)] : bt[(i)]) & 63)
  int lo = 0, hi = NNODES_;
  while (lo < hi) { int m = (lo + hi) >> 1; if (BATV(m) < b) lo = m + 1; else hi = m; }
  const int r0 = lo;
  hi = NNODES_;
  while (lo < hi) { int m = (lo + hi) >> 1; if (BATV(m) < b + 1) lo = m + 1; else hi = m; }
  const int r1 = lo;
#undef BATV
  const int c = tid & 127, half = tid >> 7;
  float acc = 0.f;
  if (isb) { const __bf16* xs = (const __bf16*)x;
    for (int r = r0 + half; r < r1; r += 2) acc += (float)xs[r * DN + c];
  } else { const float* xs = (const float*)x;
    for (int r = r0 + half; r < r1; r += 2) acc += xs[r * DN + c]; }
  __shared__ float red[256];
  red[tid] = acc;
  __syncthreads();
  if (tid < 128) ws[GXF + b * DN + tid] = red[tid] + red[tid + 128];
}

// ---- K3: edge GEMM (bf16 MFMA) + global stats + per-graph scatter ----
__global__ __launch_bounds__(256) void k_edges(
    float* __restrict__ ws, const void* __restrict__ x, const void* __restrict__ ea,
    const void* __restrict__ eidx, const void* __restrict__ batch, const int use_xbf) {
  __shared__ __align__(16) char smem[40960];   // W1^T staging, then reused as lacc
  __shared__ float lcnt[NG];
  float* lacc = (float*)smem;                  // 64*132 = 8448 floats (33,792 B)
  __bf16* w1t = (__bf16*)smem;                 // 128*160 bf16 (40,960 B)
  const int tid = threadIdx.x;
  const int* flg = (const int*)(ws + FLGF);
  const int isb = flg[0], isi = flg[1];

  // stage W1 transposed: w1t[n*160 + k] = W1[k][n]
  for (int i = tid; i < 160 * HID; i += 256) {
    const int k = i >> 7, n = i & 127;
    w1t[n * 160 + k] = (__bf16)ws[W1F_ + i];
  }
  __syncthreads();

  const int lane = tid & 63, wid = tid >> 6;
  const int ml = lane & 15, kg = lane >> 4;
  const int ch0 = (wid & 1) * 64;
  const int pair = blockIdx.x * 2 + (wid >> 1);

  bf16x8 bfr[5][4];
  float b1v[4];
#pragma unroll
  for (int nt = 0; nt < 4; ++nt) {
    const int n = ch0 + nt * 16 + ml;
    b1v[nt] = ws[B1F_ + n];
#pragma unroll
    for (int ks = 0; ks < 5; ++ks)
      bfr[ks][nt] = *(const bf16x8*)(w1t + n * 160 + ks * 32 + kg * 8);
  }
  __syncthreads();
  for (int i = tid; i < NG * 132; i += 256) lacc[i] = 0.f;
  if (tid < NG) lcnt[tid] = 0.f;
  __syncthreads();

  float s1a[4] = {0.f, 0.f, 0.f, 0.f};
  float s2a[4] = {0.f, 0.f, 0.f, 0.f};
  const int* ei32 = (const int*)eidx;
  const int* bt32 = (const int*)batch;
  const __bf16* xbq = isb ? (const __bf16*)x : (const __bf16*)(ws + XBFF);
  const int xf32 = (!isb) && (!use_xbf);

  for (int mt = pair; mt < NMT; mt += 2 * NBLK) {
    const int em = mt * 16 + ml;
    int r  = isi ? ei32[2 * em] : ei32[em];
    int cl = isi ? ei32[2 * (EE + em)] : ei32[EE + em];
    r  = min(max(r, 0), NNODES_ - 1);
    cl = min(max(cl, 0), NNODES_ - 1);
    const int gg = (isi ? bt32[2 * cl] : bt32[cl]) & 63;
    f32x4 acc[4] = {{0.f,0.f,0.f,0.f},{0.f,0.f,0.f,0.f},{0.f,0.f,0.f,0.f},{0.f,0.f,0.f,0.f}};
#pragma unroll
    for (int ks = 0; ks < 4; ++ks) {
      bf16x8 afr;
      if (xf32) {
        const float* xr = (const float*)x + r * DN + ks * 32 + kg * 8;
        const f32x4 a0 = *(const f32x4*)xr, a1 = *(const f32x4*)(xr + 4);
        afr[0]=(__bf16)a0[0]; afr[1]=(__bf16)a0[1]; afr[2]=(__bf16)a0[2]; afr[3]=(__bf16)a0[3];
        afr[4]=(__bf16)a1[0]; afr[5]=(__bf16)a1[1]; afr[6]=(__bf16)a1[2]; afr[7]=(__bf16)a1[3];
      } else {
        afr = *(const bf16x8*)(xbq + r * DN + ks * 32 + kg * 8);
      }
#pragma unroll
      for (int nt = 0; nt < 4; ++nt)
        acc[nt] = __builtin_amdgcn_mfma_f32_16x16x32_bf16(afr, bfr[ks][nt], acc[nt], 0, 0, 0);
    }
    {
      bf16x8 t;
      if (isb) {
        t = *(const bf16x8*)((const __bf16*)ea + em * DE + kg * 8);
      } else {
        const float* ep = (const float*)ea + em * DE + kg * 8;
        const f32x4 e0 = *(const f32x4*)ep, e1 = *(const f32x4*)(ep + 4);
        t[0]=(__bf16)e0[0]; t[1]=(__bf16)e0[1]; t[2]=(__bf16)e0[2]; t[3]=(__bf16)e0[3];
        t[4]=(__bf16)e1[0]; t[5]=(__bf16)e1[1]; t[6]=(__bf16)e1[2]; t[7]=(__bf16)e1[3];
      }
#pragma unroll
      for (int nt = 0; nt < 4; ++nt)
        acc[nt] = __builtin_amdgcn_mfma_f32_16x16x32_bf16(t, bfr[4][nt], acc[nt], 0, 0, 0);
    }
    int gR[4];
#pragma unroll
    for (int q = 0; q < 4; ++q) gR[q] = __shfl(gg, kg * 4 + q);
    if (((wid & 1) == 0) && kg == 0) unsafeAtomicAdd(&lcnt[gg], 1.f);
#pragma unroll
    for (int nt = 0; nt < 4; ++nt) {
      const int c = ch0 + nt * 16 + ml;
#pragma unroll
      for (int q = 0; q < 4; ++q) {
        const float v = lrelu(acc[nt][q] + b1v[nt]);
        s1a[nt] += v;
        s2a[nt] += v * v;
        unsafeAtomicAdd(&lacc[gR[q] * 132 + c], v);
      }
    }
  }
#pragma unroll
  for (int nt = 0; nt < 4; ++nt) {
    float v1 = s1a[nt], v2 = s2a[nt];
    v1 += __shfl_xor(v1, 16); v1 += __shfl_xor(v1, 32);
    v2 += __shfl_xor(v2, 16); v2 += __shfl_xor(v2, 32);
    if (lane < 16) {
      unsafeAtomicAdd(&ws[S1F + ch0 + nt * 16 + lane], v1);
      unsafeAtomicAdd(&ws[S2F + ch0 + nt * 16 + lane], v2);
    }
  }
  __syncthreads();
  for (int i = tid; i < NG * HID; i += 256)
    unsafeAtomicAdd(&ws[ACCF + i], lacc[(i >> 7) * 132 + (i & 127)]);
  if (tid < NG) unsafeAtomicAdd(&ws[CNTF + tid], lcnt[tid]);
}

// ---- K4: per-graph BN1-affine, go GEMM, layer1 of MLP2 ----
__global__ __launch_bounds__(128) void k_graph(float* __restrict__ ws) {
  const int b = blockIdx.x, c = threadIdx.x;
  const float invE = 1.f / (float)EE;
  const float mu  = ws[S1F + c] * invE;
  const float var = ws[S2F + c] * invE - mu * mu;
  const float s   = ws[G1F_ + c] * rsqrtf(var + 1e-5f);
  const float t   = ws[BE1F_ + c] - mu * s;
  const float cb  = ws[CNTF + b];
  __shared__ float zsh[HID];
  __shared__ float gv[DN + HID];
  zsh[c] = s * ws[ACCF + b * HID + c] + cb * t;
  gv[c]  = ws[GXF + b * DN + c];
  __syncthreads();
  float a = cb * ws[B2F_ + c];
  for (int k = 0; k < HID; ++k) a += zsh[k] * ws[W2F_ + k * HID + c];
  gv[DN + c] = a;
  __syncthreads();
  float h = ws[B3F_ + c];
  for (int j = 0; j < DN + HID; ++j) h += gv[j] * ws[W3F_ + j * HID + c];
  ws[O1F + b * HID + c] = lrelu(h);
}

// ---- K5: BN over 64 graphs + final Lin(128,64) ----
__global__ __launch_bounds__(64) void k_out(const float* __restrict__ ws,
                                            void* __restrict__ out) {
  const int b = blockIdx.x, o = threadIdx.x;
  const int isb = ((const int*)(ws + FLGF))[0];
  __shared__ float zrow[HID];
  for (int cc = o; cc < HID; cc += 64) {
    float sm = 0.f, sq = 0.f;
    for (int r = 0; r < NG; ++r) { const float v = ws[O1F + r * HID + cc]; sm += v; sq += v * v; }
    const float mu  = sm * (1.f / NG);
    const float var = sq * (1.f / NG) - mu * mu;
    const float sc  = ws[G3F_ + cc] * rsqrtf(var + 1e-5f);
    zrow[cc] = ws[O1F + b * HID + cc] * sc + (ws[BE3F_ + cc] - mu * sc);
  }
  __syncthreads();
  float a = ws[B4F_ + o];
  for (int k = 0; k < HID; ++k) a += zrow[k] * ws[W4F_ + k * DOUT + o];
  if (isb) ((__bf16*)out)[b * DOUT + o] = (__bf16)a;
  else     ((float*)out)[b * DOUT + o] = a;
}

extern "C" void kernel_launch(void* const* d_in, const int* in_sizes, int n_in,
                              void* d_out, int out_size, void* d_ws, size_t ws_size,
                              hipStream_t stream) {
  float* ws = (float*)d_ws;
  // ws_size is constant per session -> same decision (and same work) every call
  const int use_xbf = (ws_size >= (size_t)(WSFIX * 4 + NNODES_ * DN * 2)) ? 1 : 0;
  hipLaunchKernelGGL(k_sniff, dim3(1), dim3(64), 0, stream,
                     (const unsigned*)d_in[0], (const unsigned*)d_in[1], ws);
  hipLaunchKernelGGL(k_norm, dim3(256), dim3(256), 0, stream,
                     d_in[0],
                     d_in[5], d_in[6], d_in[7], d_in[8],
                     d_in[9], d_in[10], d_in[11], d_in[12],
                     d_in[13], d_in[14], d_in[15], d_in[16], ws, use_xbf);
  hipLaunchKernelGGL(k_gx,    dim3(NG),   dim3(256), 0, stream, d_in[0], d_in[4], ws);
  hipLaunchKernelGGL(k_edges, dim3(NBLK), dim3(256), 0, stream, ws, d_in[0], d_in[2],
                     d_in[1], d_in[4], use_xbf);
  hipLaunchKernelGGL(k_graph, dim3(NG),   dim3(128), 0, stream, ws);
  hipLaunchKernelGGL(k_out,   dim3(NG),   dim3(64),  0, stream, ws, d_out);
}